// Round 6
// baseline (1587.093 us; speedup 1.0000x reference)
//
#include <hip/hip_runtime.h>

static constexpr int D        = 64;   // N_FACTORS
static constexpr int N_LAYERS = 3;
static constexpr int SH       = 6;    // 64 rows per sort bucket
static constexpr int RPB      = 1 << SH;
static constexpr int CAP      = 3072; // max edges/bucket (mean 2048, sigma ~45)

// ---------------- bf16 helpers (RNE pack, exact unpack) ----------------
__device__ inline unsigned pack_bf2(float a, float b) {
    unsigned ua = __float_as_uint(a); ua = (ua + 0x7FFFu + ((ua >> 16) & 1u)) >> 16;
    unsigned ub = __float_as_uint(b); ub = (ub + 0x7FFFu + ((ub >> 16) & 1u)) >> 16;
    return ua | (ub << 16);
}
__device__ inline float blo(unsigned u) { return __uint_as_float(u << 16); }
__device__ inline float bhi(unsigned u) { return __uint_as_float(u & 0xFFFF0000u); }

// ===========================================================================
// k_init: acc(fp32) = emb0 ; cur(bf16) = emb0.  i indexes 8-float groups.
// ===========================================================================
__global__ void k_init_bf(const float4* __restrict__ ue, const float4* __restrict__ ie,
                          uint4* __restrict__ cur, float4* __restrict__ acc,
                          int nUser8, int nTot8) {
    int stride = gridDim.x * blockDim.x;
    for (int i = blockIdx.x * blockDim.x + threadIdx.x; i < nTot8; i += stride) {
        float4 f0, f1;
        if (i < nUser8) { f0 = ue[2 * i];              f1 = ue[2 * i + 1]; }
        else            { int j = i - nUser8; f0 = ie[2 * j]; f1 = ie[2 * j + 1]; }
        acc[2 * i]     = f0;
        acc[2 * i + 1] = f1;
        cur[i] = make_uint4(pack_bf2(f0.x, f0.y), pack_bf2(f0.z, f0.w),
                            pack_bf2(f1.x, f1.y), pack_bf2(f1.z, f1.w));
    }
}

// ===========================================================================
// Two-level edge sort.
// Level 1: bucket = row >> SH (2344 buckets), 8 XCD groups; cnt/cur layout
//          grp-major [g*NB+b] (XCD-disjoint counter lines). Bucket region of
//          b = [S[8b], S[8(b+1)}).  Level 2: per-bucket LDS counting sort
//          -> per-row sorted ecv + rowptr.
// ===========================================================================
__global__ void k_bhist(const int* __restrict__ row, int* __restrict__ cnt,
                        int nnz, int NB) {
    int g = blockIdx.x & 7;
    int stride = gridDim.x * blockDim.x;
    for (int e = blockIdx.x * blockDim.x + threadIdx.x; e < nnz; e += stride)
        atomicAdd(&cnt[g * NB + (row[e] >> SH)], 1);
}

// Single-block exclusive scan over M = NB*8 counts in (bucket-major, grp-minor)
// order; writes S[0..M] (sentinel at M) and initializes cur (grp-major).
__global__ void k_scan(const int* __restrict__ cnt, int* __restrict__ S,
                       int* __restrict__ cur, int NB, int M) {
    __shared__ int tsum[256];
    int tid = threadIdx.x;
    int per = (M + 255) / 256;
    int i0  = tid * per;
    int sum = 0;
    for (int k = 0; k < per; ++k) {
        int i = i0 + k;
        if (i < M) sum += cnt[(i & 7) * NB + (i >> 3)];
    }
    tsum[tid] = sum;
    __syncthreads();
    for (int off = 1; off < 256; off <<= 1) {
        int v = (tid >= off) ? tsum[tid - off] : 0;
        __syncthreads();
        tsum[tid] += v;
        __syncthreads();
    }
    int run = tsum[tid] - sum;
    for (int k = 0; k < per; ++k) {
        int i = i0 + k;
        if (i < M) {
            int b = i >> 3, g = i & 7;
            int c = cnt[g * NB + b];
            S[i] = run;
            cur[g * NB + b] = run;
            run += c;
        }
    }
    if (tid == 255) S[M] = tsum[255];   // == nnz
}

// Partition scatter: ecv[p] = (row_low<<18 | col, val-bits). 8192 blocks:
// enough parallel atomic chains to cover the L2 atomic round-trip (R3 ran
// this at 1024 blocks and was latency-bound at 35% occupancy).
__global__ void k_pscatter(const int* __restrict__ row, const int* __restrict__ col,
                           const float* __restrict__ val, int* __restrict__ cur,
                           int2* __restrict__ ecv, int nnz, int NB) {
    int g = blockIdx.x & 7;
    int stride = gridDim.x * blockDim.x;
    for (int e = blockIdx.x * blockDim.x + threadIdx.x; e < nnz; e += stride) {
        int r = row[e];
        int p = atomicAdd(&cur[g * NB + (r >> SH)], 1);
        ecv[p] = make_int2(((r & (RPB - 1)) << 18) | col[e], __float_as_int(val[e]));
    }
}

// Per-bucket LDS counting sort (in place) + rowptr emission.
__global__ __launch_bounds__(256) void k_bsort(const int* __restrict__ S,
                                               int2* __restrict__ ecv,
                                               int* __restrict__ rowptr,
                                               int N) {
    __shared__ int2 ebuf[CAP];          // 24 KB
    __shared__ int hist[RPB];
    __shared__ int sc[RPB];
    __shared__ int cur[RPB];
    int b    = blockIdx.x;
    int tid  = threadIdx.x;
    int base = S[b * 8];
    int cnt  = S[(b + 1) * 8] - base;
    if (cnt > CAP) cnt = CAP;           // statistically unreachable; guards LDS
    if (tid < RPB) hist[tid] = 0;
    __syncthreads();
    for (int i = tid; i < cnt; i += 256) {
        int2 e = ebuf[i] = ecv[base + i];
        atomicAdd(&hist[(unsigned)e.x >> 18], 1);
    }
    __syncthreads();
    int h = (tid < RPB) ? hist[tid] : 0;
    if (tid < RPB) sc[tid] = h;
    __syncthreads();
    for (int off = 1; off < RPB; off <<= 1) {
        int v = (tid >= off && tid < RPB) ? sc[tid - off] : 0;
        __syncthreads();
        if (tid < RPB) sc[tid] += v;
        __syncthreads();
    }
    if (tid < RPB) {
        int excl = sc[tid] - h;
        cur[tid] = excl;
        int gr = (b << SH) + tid;
        if (gr <= N) rowptr[gr] = base + excl;
    }
    __syncthreads();
    for (int i = tid; i < cnt; i += 256) {
        int2 e = ebuf[i];
        int p  = atomicAdd(&cur[(unsigned)e.x >> 18], 1);
        ecv[base + p] = make_int2(e.x & 0x3FFFF, e.y);
    }
}

// ===========================================================================
// XCD-sliced SpMM (bf16 x): wave = (row, 32B column slice). blockIdx&7 ->
// (slice = sub>>1, row-half = sub&1): slice s runs on XCD pair {2s,2s+1}
// (blockIdx%8 round-robin heuristic) so each XCD's gather working set is
// ~4.8 MB (L2-resident) instead of 19.2 MB. Lane = slot(5b) x ch(1b): 32
// edges per batch, 16B gather per lane, 8 fp32 accums, xor-reduce over slots.
// ===========================================================================
template <bool WRITE_Y, bool LAST>
__global__ __launch_bounds__(256) void k_spmm_sl(const int* __restrict__ rowptr,
                                                 const int2* __restrict__ ecv,
                                                 const uint4* __restrict__ x,
                                                 uint4* __restrict__ y,
                                                 float* __restrict__ acc, int N) {
    int bid   = blockIdx.x;
    int sub   = bid & 7;
    int slice = sub >> 1;                    // 0..3
    int half  = sub & 1;
    int r     = ((bid >> 3) << 3) + (half << 2) + (threadIdx.x >> 6);
    if (r >= N) return;
    int lane  = threadIdx.x & 63;
    int slot  = lane & 31;
    int ch    = lane >> 5;                   // 0/1
    int chunk = (slice << 1) + ch;           // uint4 index within 128B row
    int e0 = rowptr[r];
    int e1 = rowptr[r + 1];
    float a0 = 0.f, a1 = 0.f, a2 = 0.f, a3 = 0.f;
    float a4 = 0.f, a5 = 0.f, a6 = 0.f, a7 = 0.f;
    for (int base = e0; base < e1; base += 32) {
        int e = base + slot;
        int2 A = (e < e1) ? ecv[e] : make_int2(0, 0);   // val=0 for idle lanes
        float va = __int_as_float(A.y);
        uint4 xa = x[(size_t)(unsigned)A.x * 8 + chunk];
        a0 += va * blo(xa.x); a1 += va * bhi(xa.x);
        a2 += va * blo(xa.y); a3 += va * bhi(xa.y);
        a4 += va * blo(xa.z); a5 += va * bhi(xa.z);
        a6 += va * blo(xa.w); a7 += va * bhi(xa.w);
    }
    // reduce over the 5 slot bits (masks 1..16 keep ch = lane>>5 intact)
    #pragma unroll
    for (int m = 1; m <= 16; m <<= 1) {
        a0 += __shfl_xor(a0, m); a1 += __shfl_xor(a1, m);
        a2 += __shfl_xor(a2, m); a3 += __shfl_xor(a3, m);
        a4 += __shfl_xor(a4, m); a5 += __shfl_xor(a5, m);
        a6 += __shfl_xor(a6, m); a7 += __shfl_xor(a7, m);
    }
    if (slot == 0) {
        if (WRITE_Y)
            y[(size_t)r * 8 + chunk] = make_uint4(pack_bf2(a0, a1), pack_bf2(a2, a3),
                                                  pack_bf2(a4, a5), pack_bf2(a6, a7));
        size_t o = ((size_t)r << 6) + (chunk << 3);
        float4 p = *(const float4*)(acc + o);
        float4 q = *(const float4*)(acc + o + 4);
        p.x += a0; p.y += a1; p.z += a2; p.w += a3;
        q.x += a4; q.y += a5; q.z += a6; q.w += a7;
        if (LAST) {
            p.x *= 0.25f; p.y *= 0.25f; p.z *= 0.25f; p.w *= 0.25f;
            q.x *= 0.25f; q.y *= 0.25f; q.z *= 0.25f; q.w *= 0.25f;
        }
        *(float4*)(acc + o)     = p;
        *(float4*)(acc + o + 4) = q;
    }
}

// ===========================================================================
// Fallback (round-1 atomic path, fp32) if ws is too small
// ===========================================================================
__global__ void k_init(const float4* __restrict__ ue, const float4* __restrict__ ie,
                       float4* __restrict__ cur, float4* __restrict__ acc,
                       int nUser4, int nTot4) {
    int stride = gridDim.x * blockDim.x;
    for (int i = blockIdx.x * blockDim.x + threadIdx.x; i < nTot4; i += stride) {
        float4 v = (i < nUser4) ? ue[i] : ie[i - nUser4];
        cur[i] = v;
        acc[i] = v;
    }
}

__global__ void k_spmm_atomic(const int* __restrict__ row, const int* __restrict__ col,
                              const float* __restrict__ val, const float* __restrict__ x,
                              float* __restrict__ y, int nnz) {
    long long total  = (long long)nnz * 16;
    long long stride = (long long)gridDim.x * blockDim.x;
    for (long long idx = (long long)blockIdx.x * blockDim.x + threadIdx.x;
         idx < total; idx += stride) {
        int e = (int)(idx >> 4);
        int c = (int)(idx & 15);
        int r = row[e];
        int ssrc = col[e];
        float v = val[e];
        float4 xv = *(const float4*)(x + (size_t)ssrc * D + c * 4);
        float* yp = y + (size_t)r * D + c * 4;
        atomicAdd(yp + 0, v * xv.x);
        atomicAdd(yp + 1, v * xv.y);
        atomicAdd(yp + 2, v * xv.z);
        atomicAdd(yp + 3, v * xv.w);
    }
}

__global__ void k_acc(const float4* __restrict__ nxt, float4* __restrict__ acc,
                      float scale, int n4) {
    int stride = gridDim.x * blockDim.x;
    for (int i = blockIdx.x * blockDim.x + threadIdx.x; i < n4; i += stride) {
        float4 a = acc[i];
        float4 b = nxt[i];
        a.x = (a.x + b.x) * scale;
        a.y = (a.y + b.y) * scale;
        a.z = (a.z + b.z) * scale;
        a.w = (a.w + b.w) * scale;
        acc[i] = a;
    }
}

// ===========================================================================
extern "C" void kernel_launch(void* const* d_in, const int* in_sizes, int n_in,
                              void* d_out, int out_size, void* d_ws, size_t ws_size,
                              hipStream_t stream) {
    const float* ue  = (const float*)d_in[0];
    const float* ie  = (const float*)d_in[1];
    const int*   row = (const int*)  d_in[2];
    const int*   col = (const int*)  d_in[3];
    const float* val = (const float*)d_in[4];

    const int n_users = in_sizes[0] / D;
    const int n_items = in_sizes[1] / D;
    const int nnz     = in_sizes[2];
    const int N       = n_users + n_items;
    const int NB      = (N + RPB - 1) >> SH;   // 2344
    const int M       = NB * 8;

    float* acc = (float*)d_out;
    const size_t bf16B = (size_t)N * D * 2;    // 19.2 MB per layer buffer
    auto aup = [](size_t x) { return (x + 255) & ~(size_t)255; };

    size_t off = 0;
    uint4* bufA   = (uint4*)((char*)d_ws + off); off += aup(bf16B);
    uint4* bufB   = (uint4*)((char*)d_ws + off); off += aup(bf16B);
    int2*  ecv    = (int2*) ((char*)d_ws + off); off += aup((size_t)nnz * 8);
    int*   rowptr = (int*)  ((char*)d_ws + off); off += aup((size_t)(N + 1) * 4);
    int*   cnt    = (int*)  ((char*)d_ws + off); off += aup((size_t)M * 4);
    int*   cur    = (int*)  ((char*)d_ws + off); off += aup((size_t)M * 4);
    int*   S      = (int*)  ((char*)d_ws + off); off += aup((size_t)(M + 1) * 4);
    const size_t needCSR = off;

    if (ws_size >= needCSR) {
        // ---- two-level edge sort ----
        hipMemsetAsync(cnt, 0, (size_t)M * 4, stream);
        k_bhist<<<8192, 256, 0, stream>>>(row, cnt, nnz, NB);
        k_scan<<<1, 256, 0, stream>>>(cnt, S, cur, NB, M);
        k_pscatter<<<8192, 256, 0, stream>>>(row, col, val, cur, ecv, nnz, NB);
        k_bsort<<<NB, 256, 0, stream>>>(S, ecv, rowptr, N);

        // ---- init + 3 fused SpMM layers (bf16 intermediates, XCD-sliced) ----
        int nTot8  = N * 8;
        int nUser8 = n_users * 8;
        k_init_bf<<<2048, 256, 0, stream>>>((const float4*)ue, (const float4*)ie,
                                            bufA, (float4*)acc, nUser8, nTot8);
        int grid = ((N + 7) / 8) * 8;   // 8 blocks per 8-row group (4 slices x 2 halves)
        k_spmm_sl<true,  false><<<grid, 256, 0, stream>>>(rowptr, ecv, bufA, bufB, acc, N);
        k_spmm_sl<true,  false><<<grid, 256, 0, stream>>>(rowptr, ecv, bufB, bufA, acc, N);
        k_spmm_sl<false, true ><<<grid, 256, 0, stream>>>(rowptr, ecv, bufA, bufA, acc, N);
    } else {
        // ---- fallback: atomic scatter path (fp32) ----
        const size_t denseB = (size_t)N * D * sizeof(float);
        float* fa = (float*)d_ws;
        float* fb = fa + (size_t)N * D;
        const int nTot4  = N * D / 4;
        const int nUser4 = n_users * D / 4;
        k_init<<<2048, 256, 0, stream>>>((const float4*)ue, (const float4*)ie,
                                         (float4*)fa, (float4*)acc, nUser4, nTot4);
        float* curp = fa;
        float* nxt  = fb;
        for (int l = 0; l < N_LAYERS; ++l) {
            hipMemsetAsync(nxt, 0, denseB, stream);
            k_spmm_atomic<<<8192, 256, 0, stream>>>(row, col, val, curp, nxt, nnz);
            float scale = (l == N_LAYERS - 1) ? (1.0f / (N_LAYERS + 1)) : 1.0f;
            k_acc<<<2048, 256, 0, stream>>>((const float4*)nxt, (float4*)acc, scale, nTot4);
            float* t = curp; curp = nxt; nxt = t;
        }
    }
}

// Round 7
// 563.495 us; speedup vs baseline: 2.8165x; 2.8165x over previous
//
#include <hip/hip_runtime.h>

static constexpr int D        = 64;   // N_FACTORS
static constexpr int N_LAYERS = 3;
static constexpr int SH2      = 8;    // coarse bucket = 256 rows
static constexpr int T1       = 4096; // edges per pass-1 tile

// ---------------- bf16 helpers (RNE pack, exact unpack) ----------------
__device__ inline unsigned pack_bf2(float a, float b) {
    unsigned ua = __float_as_uint(a); ua = (ua + 0x7FFFu + ((ua >> 16) & 1u)) >> 16;
    unsigned ub = __float_as_uint(b); ub = (ub + 0x7FFFu + ((ub >> 16) & 1u)) >> 16;
    return ua | (ub << 16);
}
__device__ inline float blo(unsigned u) { return __uint_as_float(u << 16); }
__device__ inline float bhi(unsigned u) { return __uint_as_float(u & 0xFFFF0000u); }

// ===========================================================================
// k_init: acc(fp32) = emb0 ; cur(bf16) = emb0.  i indexes 8-float groups.
// ===========================================================================
__global__ void k_init_bf(const float4* __restrict__ ue, const float4* __restrict__ ie,
                          uint4* __restrict__ cur, float4* __restrict__ acc,
                          int nUser8, int nTot8) {
    int stride = gridDim.x * blockDim.x;
    for (int i = blockIdx.x * blockDim.x + threadIdx.x; i < nTot8; i += stride) {
        float4 f0, f1;
        if (i < nUser8) { f0 = ue[2 * i];              f1 = ue[2 * i + 1]; }
        else            { int j = i - nUser8; f0 = ie[2 * j]; f1 = ie[2 * j + 1]; }
        acc[2 * i]     = f0;
        acc[2 * i + 1] = f1;
        cur[i] = make_uint4(pack_bf2(f0.x, f0.y), pack_bf2(f0.z, f0.w),
                            pack_bf2(f1.x, f1.y), pack_bf2(f1.z, f1.w));
    }
}

// ===========================================================================
// Coarse histogram with LDS pre-aggregation (586 buckets of 256 rows).
// ===========================================================================
__global__ void k_hist2(const int* __restrict__ row, int* __restrict__ gcnt,
                        int nnz, int NB2) {
    extern __shared__ int h[];            // NB2 ints
    for (int b = threadIdx.x; b < NB2; b += 256) h[b] = 0;
    __syncthreads();
    int stride = gridDim.x * blockDim.x;
    for (int e = blockIdx.x * blockDim.x + threadIdx.x; e < nnz; e += stride)
        atomicAdd(&h[row[e] >> SH2], 1);
    __syncthreads();
    for (int b = threadIdx.x; b < NB2; b += 256)
        if (h[b]) atomicAdd(&gcnt[b], h[b]);
}

// Single-block exclusive scan of NB2 counts -> S[0..NB2] and cursor copy.
__global__ void k_scan2(const int* __restrict__ gcnt, int* __restrict__ S,
                        int* __restrict__ cursor, int NB2, int nnz) {
    __shared__ int ssum[256];
    int tid = threadIdx.x;
    int per = (NB2 + 255) / 256;
    int i0  = tid * per;
    int sum = 0;
    for (int k = 0; k < per; ++k) {
        int i = i0 + k;
        if (i < NB2) sum += gcnt[i];
    }
    ssum[tid] = sum;
    __syncthreads();
    for (int off = 1; off < 256; off <<= 1) {
        int v = (tid >= off) ? ssum[tid - off] : 0;
        __syncthreads();
        ssum[tid] += v;
        __syncthreads();
    }
    int run = ssum[tid] - sum;
    for (int k = 0; k < per; ++k) {
        int i = i0 + k;
        if (i < NB2) {
            S[i] = run;
            cursor[i] = run;
            run += gcnt[i];
        }
    }
    if (tid == 255) S[NB2] = nnz;
}

// ===========================================================================
// Pass 1: tile-LDS radix partition into coarse buckets. Each block takes one
// tile of T1 edges, bins them in LDS, reserves per-bucket global ranges (one
// atomic per (tile,bucket)), and writes bin-sorted runs coalesced.
// gout[p] = ((row&255)<<18 | col, val-bits); bucket known from position.
// ===========================================================================
__global__ __launch_bounds__(256) void k_part1(const int* __restrict__ row,
                                               const int* __restrict__ col,
                                               const float* __restrict__ val,
                                               int* __restrict__ cursor,
                                               int2* __restrict__ gout,
                                               int nnz, int NB2) {
    __shared__ int2 ebuf[T1];                 // 32 KB
    __shared__ unsigned short bbin[T1];       // 8 KB
    __shared__ unsigned short perm[T1];       // 8 KB
    __shared__ int hist[768];                 // >= NB2
    __shared__ int binstart[768];
    __shared__ int gcur[768];
    __shared__ int bincur[768];
    __shared__ int ssum[256];

    int tid   = threadIdx.x;
    int base  = blockIdx.x * T1;
    int n     = nnz - base; if (n > T1) n = T1;

    for (int b = tid; b < NB2; b += 256) { hist[b] = 0; bincur[b] = 0; }
    __syncthreads();

    // load + bin + histogram
    for (int i = tid; i < n; i += 256) {
        int e = base + i;
        int r = row[e];
        ebuf[i] = make_int2(((r & ((1 << SH2) - 1)) << 18) | col[e],
                            __float_as_int(val[e]));
        int b = r >> SH2;
        bbin[i] = (unsigned short)b;
        atomicAdd(&hist[b], 1);
    }
    __syncthreads();

    // exclusive scan of hist -> binstart (3 bins per thread)
    int per = (NB2 + 255) / 256;              // 3
    int i0  = tid * per;
    int sum = 0;
    for (int k = 0; k < per; ++k) { int i = i0 + k; if (i < NB2) sum += hist[i]; }
    ssum[tid] = sum;
    __syncthreads();
    for (int off = 1; off < 256; off <<= 1) {
        int v = (tid >= off) ? ssum[tid - off] : 0;
        __syncthreads();
        ssum[tid] += v;
        __syncthreads();
    }
    int run = ssum[tid] - sum;
    for (int k = 0; k < per; ++k) {
        int i = i0 + k;
        if (i < NB2) { binstart[i] = run; run += hist[i]; }
    }
    __syncthreads();

    // reserve global ranges
    for (int b = tid; b < NB2; b += 256) {
        int c = hist[b];
        if (c) gcur[b] = atomicAdd(&cursor[b], c);
    }
    __syncthreads();

    // rank within tile
    for (int i = tid; i < n; i += 256) {
        int b = bbin[i];
        int rnk = binstart[b] + atomicAdd(&bincur[b], 1);
        perm[rnk] = (unsigned short)i;
    }
    __syncthreads();

    // coalesced write of bin-sorted runs
    for (int j = tid; j < n; j += 256) {
        int i = perm[j];
        int b = bbin[i];
        gout[gcur[b] + (j - binstart[b])] = ebuf[i];
    }
}

// ===========================================================================
// Pass 2: one block per coarse bucket (~8.2k edges, 64 KB window). Hist over
// 256 local rows -> rowptr; then scatter within the window (L2-merged) into
// final per-row-sorted ecv[p] = (col, val-bits).
// ===========================================================================
__global__ __launch_bounds__(256) void k_part2(const int* __restrict__ S,
                                               const int2* __restrict__ gout,
                                               int2* __restrict__ ecv,
                                               int* __restrict__ rowptr) {
    __shared__ int hist[256];
    __shared__ int cur[256];
    __shared__ int ssum[256];
    int b   = blockIdx.x;
    int tid = threadIdx.x;
    int lo  = S[b];
    int cnt = S[b + 1] - lo;

    hist[tid] = 0;
    __syncthreads();
    for (int i = tid; i < cnt; i += 256)
        atomicAdd(&hist[(unsigned)gout[lo + i].x >> 18], 1);
    __syncthreads();

    int h = hist[tid];
    ssum[tid] = h;
    __syncthreads();
    for (int off = 1; off < 256; off <<= 1) {
        int v = (tid >= off) ? ssum[tid - off] : 0;
        __syncthreads();
        ssum[tid] += v;
        __syncthreads();
    }
    int excl = ssum[tid] - h;
    cur[tid] = excl;
    rowptr[(b << SH2) + tid] = lo + excl;
    __syncthreads();

    for (int i = tid; i < cnt; i += 256) {
        int2 e = gout[lo + i];
        int r  = (unsigned)e.x >> 18;
        int p  = atomicAdd(&cur[r], 1);
        ecv[lo + p] = make_int2(e.x & 0x3FFFF, e.y);
    }
}

// ===========================================================================
// SpMM (bf16 x): one wave per row. lane = grp*8 + ch; 8 edge-groups per wave,
// lane gathers 16 B (= 8 bf16) of x[col]. fp32 accumulate, unroll 2.
// shfl_xor(8,16,32) reduce; fused acc(fp32) update; y written bf16.
// (R5-proven structure — sector-optimal 128 B/edge gathers; do not slice D.)
// ===========================================================================
template <bool WRITE_Y, bool LAST>
__global__ void k_spmm_bf(const int* __restrict__ rowptr, const int2* __restrict__ ecv,
                          const uint4* __restrict__ x, uint4* __restrict__ y,
                          float* __restrict__ acc, int N) {
    int wid = (blockIdx.x * blockDim.x + threadIdx.x) >> 6;
    if (wid >= N) return;
    int lane = threadIdx.x & 63;
    int grp  = lane >> 3;          // edge slot within wave [0,8)
    int ch   = lane & 7;           // 16B chunk of the 128B bf16 row
    int e0 = rowptr[wid];
    int e1 = rowptr[wid + 1];
    float s0 = 0.f, s1 = 0.f, s2 = 0.f, s3 = 0.f;
    float s4 = 0.f, s5 = 0.f, s6 = 0.f, s7 = 0.f;
    int e = e0 + grp;
    for (; e + 8 < e1; e += 16) {
        int2 A = ecv[e];
        int2 C = ecv[e + 8];
        uint4 xa = x[(size_t)A.x * 8 + ch];
        uint4 xc = x[(size_t)C.x * 8 + ch];
        float va = __int_as_float(A.y);
        float vc = __int_as_float(C.y);
        s0 += va * blo(xa.x) + vc * blo(xc.x);
        s1 += va * bhi(xa.x) + vc * bhi(xc.x);
        s2 += va * blo(xa.y) + vc * blo(xc.y);
        s3 += va * bhi(xa.y) + vc * bhi(xc.y);
        s4 += va * blo(xa.z) + vc * blo(xc.z);
        s5 += va * bhi(xa.z) + vc * bhi(xc.z);
        s6 += va * blo(xa.w) + vc * blo(xc.w);
        s7 += va * bhi(xa.w) + vc * bhi(xc.w);
    }
    if (e < e1) {
        int2 A = ecv[e];
        uint4 xa = x[(size_t)A.x * 8 + ch];
        float va = __int_as_float(A.y);
        s0 += va * blo(xa.x); s1 += va * bhi(xa.x);
        s2 += va * blo(xa.y); s3 += va * bhi(xa.y);
        s4 += va * blo(xa.z); s5 += va * bhi(xa.z);
        s6 += va * blo(xa.w); s7 += va * bhi(xa.w);
    }
    #pragma unroll
    for (int m = 8; m <= 32; m <<= 1) {
        s0 += __shfl_xor(s0, m); s1 += __shfl_xor(s1, m);
        s2 += __shfl_xor(s2, m); s3 += __shfl_xor(s3, m);
        s4 += __shfl_xor(s4, m); s5 += __shfl_xor(s5, m);
        s6 += __shfl_xor(s6, m); s7 += __shfl_xor(s7, m);
    }
    if (grp == 0) {
        if (WRITE_Y)
            y[(size_t)wid * 8 + ch] = make_uint4(pack_bf2(s0, s1), pack_bf2(s2, s3),
                                                 pack_bf2(s4, s5), pack_bf2(s6, s7));
        size_t o = ((size_t)wid << 6) + (ch << 3);
        float4 a0 = *(const float4*)(acc + o);
        float4 a1 = *(const float4*)(acc + o + 4);
        a0.x += s0; a0.y += s1; a0.z += s2; a0.w += s3;
        a1.x += s4; a1.y += s5; a1.z += s6; a1.w += s7;
        if (LAST) {
            a0.x *= 0.25f; a0.y *= 0.25f; a0.z *= 0.25f; a0.w *= 0.25f;
            a1.x *= 0.25f; a1.y *= 0.25f; a1.z *= 0.25f; a1.w *= 0.25f;
        }
        *(float4*)(acc + o)     = a0;
        *(float4*)(acc + o + 4) = a1;
    }
}

// ===========================================================================
// Fallback (round-1 atomic path, fp32) if ws is too small
// ===========================================================================
__global__ void k_init(const float4* __restrict__ ue, const float4* __restrict__ ie,
                       float4* __restrict__ cur, float4* __restrict__ acc,
                       int nUser4, int nTot4) {
    int stride = gridDim.x * blockDim.x;
    for (int i = blockIdx.x * blockDim.x + threadIdx.x; i < nTot4; i += stride) {
        float4 v = (i < nUser4) ? ue[i] : ie[i - nUser4];
        cur[i] = v;
        acc[i] = v;
    }
}

__global__ void k_spmm_atomic(const int* __restrict__ row, const int* __restrict__ col,
                              const float* __restrict__ val, const float* __restrict__ x,
                              float* __restrict__ y, int nnz) {
    long long total  = (long long)nnz * 16;
    long long stride = (long long)gridDim.x * blockDim.x;
    for (long long idx = (long long)blockIdx.x * blockDim.x + threadIdx.x;
         idx < total; idx += stride) {
        int e = (int)(idx >> 4);
        int c = (int)(idx & 15);
        int r = row[e];
        int ssrc = col[e];
        float v = val[e];
        float4 xv = *(const float4*)(x + (size_t)ssrc * D + c * 4);
        float* yp = y + (size_t)r * D + c * 4;
        atomicAdd(yp + 0, v * xv.x);
        atomicAdd(yp + 1, v * xv.y);
        atomicAdd(yp + 2, v * xv.z);
        atomicAdd(yp + 3, v * xv.w);
    }
}

__global__ void k_acc(const float4* __restrict__ nxt, float4* __restrict__ acc,
                      float scale, int n4) {
    int stride = gridDim.x * blockDim.x;
    for (int i = blockIdx.x * blockDim.x + threadIdx.x; i < n4; i += stride) {
        float4 a = acc[i];
        float4 b = nxt[i];
        a.x = (a.x + b.x) * scale;
        a.y = (a.y + b.y) * scale;
        a.z = (a.z + b.z) * scale;
        a.w = (a.w + b.w) * scale;
        acc[i] = a;
    }
}

// ===========================================================================
extern "C" void kernel_launch(void* const* d_in, const int* in_sizes, int n_in,
                              void* d_out, int out_size, void* d_ws, size_t ws_size,
                              hipStream_t stream) {
    const float* ue  = (const float*)d_in[0];
    const float* ie  = (const float*)d_in[1];
    const int*   row = (const int*)  d_in[2];
    const int*   col = (const int*)  d_in[3];
    const float* val = (const float*)d_in[4];

    const int n_users = in_sizes[0] / D;
    const int n_items = in_sizes[1] / D;
    const int nnz     = in_sizes[2];
    const int N       = n_users + n_items;
    const int NB2     = (N + (1 << SH2) - 1) >> SH2;   // 586

    float* acc = (float*)d_out;
    const size_t bf16B = (size_t)N * D * 2;    // 19.2 MB per layer buffer
    auto aup = [](size_t x) { return (x + 255) & ~(size_t)255; };

    size_t off = 0;
    uint4* bufA   = (uint4*)((char*)d_ws + off); off += aup(bf16B);
    uint4* bufB   = (uint4*)((char*)d_ws + off); off += aup(bf16B);
    int2*  gout   = (int2*) ((char*)d_ws + off); off += aup((size_t)nnz * 8);
    int2*  ecv    = (int2*) ((char*)d_ws + off); off += aup((size_t)nnz * 8);
    int*   rowptr = (int*)  ((char*)d_ws + off); off += aup((size_t)(NB2 << SH2) * 4);
    int*   gcnt   = (int*)  ((char*)d_ws + off); off += aup((size_t)NB2 * 4);
    int*   cursor = (int*)  ((char*)d_ws + off); off += aup((size_t)NB2 * 4);
    int*   S      = (int*)  ((char*)d_ws + off); off += aup((size_t)(NB2 + 1) * 4);
    const size_t needCSR = off;

    if (ws_size >= needCSR) {
        // ---- two-pass radix partition -> per-row CSR ----
        hipMemsetAsync(gcnt, 0, (size_t)NB2 * 4, stream);
        k_hist2<<<1024, 256, NB2 * 4, stream>>>(row, gcnt, nnz, NB2);
        k_scan2<<<1, 256, 0, stream>>>(gcnt, S, cursor, NB2, nnz);
        int nTiles = (nnz + T1 - 1) / T1;      // 1172
        k_part1<<<nTiles, 256, 0, stream>>>(row, col, val, cursor, gout, nnz, NB2);
        k_part2<<<NB2, 256, 0, stream>>>(S, gout, ecv, rowptr);

        // ---- init + 3 fused SpMM layers (bf16 intermediates) ----
        int nTot8  = N * 8;
        int nUser8 = n_users * 8;
        k_init_bf<<<2048, 256, 0, stream>>>((const float4*)ue, (const float4*)ie,
                                            bufA, (float4*)acc, nUser8, nTot8);
        int grid = (N + 3) / 4;   // one wave per row
        k_spmm_bf<true,  false><<<grid, 256, 0, stream>>>(rowptr, ecv, bufA, bufB, acc, N);
        k_spmm_bf<true,  false><<<grid, 256, 0, stream>>>(rowptr, ecv, bufB, bufA, acc, N);
        k_spmm_bf<false, true ><<<grid, 256, 0, stream>>>(rowptr, ecv, bufA, bufA, acc, N);
    } else {
        // ---- fallback: atomic scatter path (fp32) ----
        const size_t denseB = (size_t)N * D * sizeof(float);
        float* fa = (float*)d_ws;
        float* fb = fa + (size_t)N * D;
        const int nTot4  = N * D / 4;
        const int nUser4 = n_users * D / 4;
        k_init<<<2048, 256, 0, stream>>>((const float4*)ue, (const float4*)ie,
                                         (float4*)fa, (float4*)acc, nUser4, nTot4);
        float* curp = fa;
        float* nxt  = fb;
        for (int l = 0; l < N_LAYERS; ++l) {
            hipMemsetAsync(nxt, 0, denseB, stream);
            k_spmm_atomic<<<8192, 256, 0, stream>>>(row, col, val, curp, nxt, nnz);
            float scale = (l == N_LAYERS - 1) ? (1.0f / (N_LAYERS + 1)) : 1.0f;
            k_acc<<<2048, 256, 0, stream>>>((const float4*)nxt, (float4*)acc, scale, nTot4);
            float* t = curp; curp = nxt; nxt = t;
        }
    }
}